// Round 2
// baseline (1468.116 us; speedup 1.0000x reference)
//
#include <hip/hip_runtime.h>
#include <stdint.h>
#include <math.h>

#define TOK   2048
#define HD    2880
#define NEXP  8
#define NPAIR 4096
#define N1    5760
#define KDIM  2880
#define BM    256
#define BN    64
#define BK    64
#define ROWCAP 4480

typedef float  f32x4  __attribute__((ext_vector_type(4)));
typedef __bf16 bf16x8 __attribute__((ext_vector_type(8)));

#if defined(__has_builtin)
#if __has_builtin(__builtin_amdgcn_global_load_lds)
#define ASYNC_OK 1
#endif
#endif
#ifndef ASYNC_OK
#define ASYNC_OK 0
#endif

__device__ __forceinline__ unsigned short f2bf(float f) {
  union { float f; uint32_t u; } v; v.f = f;
  return (unsigned short)((v.u + 0x7FFFu + ((v.u >> 16) & 1u)) >> 16);
}

__device__ __forceinline__ void stage16(void* lds_base, const void* g, int lane) {
#if ASYNC_OK
  __builtin_amdgcn_global_load_lds((const __attribute__((address_space(1))) void*)g,
                                   (__attribute__((address_space(3))) void*)lds_base,
                                   16, 0, 0);
#else
  *(float4*)((char*)lds_base + lane * 16) = *(const float4*)g;
#endif
}

// ---------------- kernel 0: zero counts + cursors ----------------
__global__ void k_init(int* meta) {
  if (threadIdx.x < 16) meta[threadIdx.x] = 0;
}

// ---------------- kernel 0b: zero output (gemm<1> accumulates atomically) ----------------
__global__ __launch_bounds__(256) void k_zero(float* out) {
  size_t i = (size_t)blockIdx.x * 256 + threadIdx.x;
  ((float4*)out)[i] = (float4){0.f, 0.f, 0.f, 0.f};
}

// ---------------- kernel 1: router ----------------
__global__ __launch_bounds__(256) void k_router(
    const float* __restrict__ x, const float* __restrict__ rw,
    const float* __restrict__ rb, int* __restrict__ meta,
    int* __restrict__ topk_i, float* __restrict__ topk_w) {
  int t = blockIdx.x;
  int tid = threadIdx.x;
  const float* xr = x + (size_t)t * HD;
  float part[NEXP];
  #pragma unroll
  for (int e = 0; e < NEXP; e++) part[e] = 0.f;
  for (int i = tid; i < HD; i += 256) {
    float xv = xr[i];
    const float* w = rw + (size_t)i * NEXP;
    #pragma unroll
    for (int e = 0; e < NEXP; e++) part[e] += xv * w[e];
  }
  #pragma unroll
  for (int e = 0; e < NEXP; e++)
    for (int o = 32; o > 0; o >>= 1) part[e] += __shfl_down(part[e], o, 64);
  __shared__ float sred[4][NEXP];
  int wave = tid >> 6, lane = tid & 63;
  if (lane == 0)
    for (int e = 0; e < NEXP; e++) sred[wave][e] = part[e];
  __syncthreads();
  if (tid == 0) {
    float l[NEXP];
    for (int e = 0; e < NEXP; e++)
      l[e] = rb[e] + sred[0][e] + sred[1][e] + sred[2][e] + sred[3][e];
    int e0 = 0;
    for (int e = 1; e < NEXP; e++) if (l[e] > l[e0]) e0 = e;
    int e1 = -1;
    for (int e = 0; e < NEXP; e++) {
      if (e == e0) continue;
      if (e1 < 0 || l[e] > l[e1]) e1 = e;
    }
    float w0 = 1.f / (1.f + expf(l[e1] - l[e0]));
    topk_i[2 * t] = e0; topk_i[2 * t + 1] = e1;
    topk_w[2 * t] = w0; topk_w[2 * t + 1] = 1.f - w0;
    atomicAdd(&meta[e0], 1); atomicAdd(&meta[e1], 1);
  }
}

// ---------------- kernel 2: scan (expert offsets padded to 8 rows) ----------------
__global__ void k_scan(int* meta) {
  if (threadIdx.x == 0) {
    int off = 0, toff = 0;
    meta[16] = 0; meta[32] = 0;
    for (int e = 0; e < NEXP; e++) {
      int c = meta[e];
      off += (c + 7) & ~7;        meta[16 + e + 1] = off;
      toff += (c + BM - 1) / BM;  meta[32 + e + 1] = toff;
    }
  }
}

// ---------------- kernel 3: dispatch + gather x -> bf16 (XOR-swizzled rows) ----------------
// Row layout: 45 segments of 128B; 16B block b of each segment stored at
// position b ^ (row & 7).  Linear global_load_lds staging then yields a
// bank-conflict-free ds_read_b128 fragment pattern in the GEMM.
__global__ __launch_bounds__(256) void k_gather(
    const float* __restrict__ x, const int* __restrict__ topk_i,
    const float* __restrict__ topk_w, int* __restrict__ meta,
    int* __restrict__ row_tok, float* __restrict__ row_w,
    unsigned short* __restrict__ A) {
  int p = blockIdx.x;
  __shared__ int spos;
  if (threadIdx.x == 0) {
    int e = topk_i[p];
    int pos = meta[16 + e] + atomicAdd(&meta[8 + e], 1);
    spos = pos;
    row_tok[pos] = p >> 1;
    row_w[pos] = topk_w[p];
  }
  __syncthreads();
  int pos = spos;
  int sw = pos & 7;
  int t = p >> 1;
  const float4* xr = (const float4*)(x + (size_t)t * HD);
  unsigned short* dst = A + (size_t)pos * HD;
  for (int i = threadIdx.x; i < HD / 4; i += 256) {
    float4 v = xr[i];
    uint2 u;
    u.x = (uint32_t)f2bf(v.x) | ((uint32_t)f2bf(v.y) << 16);
    u.y = (uint32_t)f2bf(v.z) | ((uint32_t)f2bf(v.w) << 16);
    int seg = i >> 4, j = i & 15;
    int b = (j >> 1) ^ sw, rr = j & 1;
    *(uint2*)(dst + seg * 64 + b * 8 + rr * 4) = u;
  }
}

// ---------------- kernel 4: weight convert fp32 [E][K][N] -> bf16 [E][cc][K], swizzled ----------------
// Output row n (slice-local), 128B segment s: 16B block position b holds
// logical k-block b ^ (n & 7) -- same convention as Abuf, so the GEMM uses
// one staging + fragment-read path for both operands.
__global__ __launch_bounds__(256) void k_convert(
    const float* __restrict__ in, unsigned short* __restrict__ outb,
    int rowLen, int c0, int cc) {
  int e = blockIdx.z;
  int k0 = blockIdx.x * 64;
  int n0 = blockIdx.y * 64;          // slice-local col base
  __shared__ unsigned short T[64 * 64];   // 8 KB
  int tid = threadIdx.x;
  int n = tid & 63;
  int g = tid >> 6;                   // 0..3, one wave each
  const float* src = in + (size_t)e * KDIM * rowLen + (size_t)k0 * rowLen + (c0 + n0 + n);
  #pragma unroll
  for (int kb = g * 2; kb < g * 2 + 2; kb++) {
    uint32_t d0, d1, d2, d3;
    {
      float a0 = src[(size_t)(kb * 8 + 0) * rowLen];
      float a1 = src[(size_t)(kb * 8 + 1) * rowLen];
      float a2 = src[(size_t)(kb * 8 + 2) * rowLen];
      float a3 = src[(size_t)(kb * 8 + 3) * rowLen];
      float a4 = src[(size_t)(kb * 8 + 4) * rowLen];
      float a5 = src[(size_t)(kb * 8 + 5) * rowLen];
      float a6 = src[(size_t)(kb * 8 + 6) * rowLen];
      float a7 = src[(size_t)(kb * 8 + 7) * rowLen];
      d0 = (uint32_t)f2bf(a0) | ((uint32_t)f2bf(a1) << 16);
      d1 = (uint32_t)f2bf(a2) | ((uint32_t)f2bf(a3) << 16);
      d2 = (uint32_t)f2bf(a4) | ((uint32_t)f2bf(a5) << 16);
      d3 = (uint32_t)f2bf(a6) | ((uint32_t)f2bf(a7) << 16);
    }
    uint4 v; v.x = d0; v.y = d1; v.z = d2; v.w = d3;
    int phys = n * 128 + ((kb ^ (n & 7)) << 4);
    *(uint4*)((char*)T + phys) = v;
  }
  __syncthreads();
  size_t obase = (size_t)e * cc * KDIM;
  #pragma unroll
  for (int it = 0; it < 2; it++) {
    int c = tid + it * 256;
    int r = c >> 3, b = c & 7;
    uint4 v = *(const uint4*)((const char*)T + r * 128 + b * 16);
    char* dst = (char*)(outb + obase + (size_t)(n0 + r) * KDIM + k0) + b * 16;
    *(uint4*)dst = v;                   // coalesced 128B per 8 lanes
  }
}

// ---------------- grouped GEMM: both operands bf16, global_load_lds staged, swizzled ----------------
// MODE 0: gate_up + GLU -> act bf16 (swizzled rows)
// MODE 1: down + bias, * routing weight, atomicAdd fp32 into out[token]
template <int MODE>
__global__ __launch_bounds__(256, 3) void k_gemm(
    const unsigned short* __restrict__ A, const unsigned short* __restrict__ Bt,
    const float* __restrict__ bias, const int* __restrict__ meta,
    const int* __restrict__ row_tok, const float* __restrict__ row_w,
    unsigned short* __restrict__ outb, float* __restrict__ outf,
    int c0, int cc) {
  constexpr int NB = (MODE == 0) ? N1 : HD;   // bias stride per expert
  const int* toff = meta + 32;
  int mt = blockIdx.x;
  if (mt >= toff[NEXP]) return;
  int e = 0;
  while (mt >= toff[e + 1]) e++;
  const int* off = meta + 16;
  int row0 = off[e] + (mt - toff[e]) * BM;          // 8-aligned
  int rows_valid = meta[e] - (mt - toff[e]) * BM;   // true count based
  int nb0 = blockIdx.y * BN;                        // slice-local

  __shared__ unsigned short As[BM * BK];  // 32 KB, pre-swizzled content
  __shared__ unsigned short Bs[BN * BK];  //  8 KB, pre-swizzled content

  int tid = threadIdx.x;
  int lane = tid & 63, wave = tid >> 6;
  int q = lane >> 4, nl = lane & 15;

  const unsigned short* Bexp = Bt + (size_t)e * cc * KDIM;
  bool wave_active = (wave * 64) < rows_valid;

  f32x4 acc[4][4];
  #pragma unroll
  for (int i = 0; i < 4; i++)
    #pragma unroll
    for (int j = 0; j < 4; j++) acc[i][j] = (f32x4){0.f, 0.f, 0.f, 0.f};

  const char* gA = (const char*)(A + (size_t)(row0 + wave * 64 + (lane >> 3)) * KDIM)
                   + (lane & 7) * 16;
  const char* gB = (const char*)(Bexp + (size_t)(nb0 + wave * 16 + (lane >> 3)) * KDIM)
                   + (lane & 7) * 16;

  for (int kt = 0; kt < KDIM / BK; kt++) {
    // ---- stage A tile (256 x 64 bf16): 8 x 1KB per wave ----
    #pragma unroll
    for (int i = 0; i < 8; i++) {
      char* lb = (char*)As + (wave * 64 + i * 8) * (BK * 2);
      stage16(lb, gA + (size_t)kt * (BK * 2) + (size_t)i * 8 * (KDIM * 2), lane);
    }
    // ---- stage B tile (64 x 64 bf16): 2 x 1KB per wave ----
    #pragma unroll
    for (int i = 0; i < 2; i++) {
      char* lb = (char*)Bs + (wave * 16 + i * 8) * (BK * 2);
      stage16(lb, gB + (size_t)kt * (BK * 2) + (size_t)i * 8 * (KDIM * 2), lane);
    }
    __syncthreads();
    if (wave_active) {
      #pragma unroll
      for (int s = 0; s < 2; s++) {
        bf16x8 af[4], bfr[4];
        #pragma unroll
        for (int mi = 0; mi < 4; mi++) {
          int row = wave * 64 + mi * 16 + nl;
          int blk = (s * 4 + q) ^ (row & 7);
          af[mi] = *(const bf16x8*)((const char*)As + row * (BK * 2) + (blk << 4));
        }
        #pragma unroll
        for (int nj = 0; nj < 4; nj++) {
          int rowb = nj * 16 + nl;
          int blk = (s * 4 + q) ^ (rowb & 7);
          bfr[nj] = *(const bf16x8*)((const char*)Bs + rowb * (BK * 2) + (blk << 4));
        }
        #pragma unroll
        for (int mi = 0; mi < 4; mi++)
          #pragma unroll
          for (int nj = 0; nj < 4; nj++)
            acc[mi][nj] = __builtin_amdgcn_mfma_f32_16x16x32_bf16(af[mi], bfr[nj], acc[mi][nj], 0, 0, 0);
      }
    }
    __syncthreads();
  }

  if (!wave_active) return;
  #pragma unroll
  for (int mi = 0; mi < 4; mi++) {
    int rl = wave * 64 + mi * 16 + q * 4;
    int tokv[4]; float wvv[4];
    if (MODE == 1) {
      #pragma unroll
      for (int r = 0; r < 4; r++) {
        int arow = row0 + rl + r;
        tokv[r] = row_tok[arow];
        wvv[r] = row_w[arow];
      }
    }
    #pragma unroll
    for (int nj = 0; nj < 4; nj++) {
      int n = c0 + nb0 + nj * 16 + nl;   // global output column
      float bv = bias[(size_t)e * NB + n];
      #pragma unroll
      for (int r = 0; r < 4; r++) {
        float v = acc[mi][nj][r] + bv;
        float partner = __shfl_xor(v, 1, 64);
        if (MODE == 0) {
          if ((nl & 1) == 0 && (rl + r) < rows_valid) {
            float gg = fminf(v, 7.0f);                      // gate clamp (max only)
            float u = fminf(fmaxf(partner, -7.0f), 7.0f);   // up clamp
            float glu = gg / (1.0f + expf(-1.702f * gg));
            int col = n >> 1;
            int arow = row0 + rl + r;
            int us = ((col >> 6) << 6) + ((((col >> 3) & 7) ^ (arow & 7)) << 3) + (col & 7);
            outb[(size_t)arow * HD + us] = f2bf((u + 1.0f) * glu);
          }
        } else {
          if ((rl + r) < rows_valid)
            atomicAdd(&outf[(size_t)tokv[r] * HD + n], wvv[r] * v);
        }
      }
    }
  }
}

extern "C" void kernel_launch(void* const* d_in, const int* in_sizes, int n_in,
                              void* d_out, int out_size, void* d_ws, size_t ws_size,
                              hipStream_t stream) {
  const float* x   = (const float*)d_in[0];
  const float* rw  = (const float*)d_in[1];
  const float* rb  = (const float*)d_in[2];
  const float* gup = (const float*)d_in[3];
  const float* gub = (const float*)d_in[4];
  const float* dwn = (const float*)d_in[5];
  const float* dwb = (const float*)d_in[6];
  float* out = (float*)d_out;

  char* ws = (char*)d_ws;
  int* meta = (int*)ws;                         // counts[8] cursors[8] offsets[9] toff[9]
  int* topk_i = meta + 64;                      // 4096
  float* topk_w = (float*)(topk_i + NPAIR);     // 4096
  int* row_tok = (int*)(topk_w + NPAIR);        // ROWCAP
  float* row_w = (float*)(row_tok + ROWCAP);    // ROWCAP
  size_t ofs = (((size_t)((char*)(row_w + ROWCAP) - ws)) + 255) & ~(size_t)255;
  unsigned short* Abuf = (unsigned short*)(ws + ofs);
  unsigned short* act  = Abuf + (size_t)ROWCAP * HD;
  size_t ofs2 = (((size_t)((char*)(act + (size_t)ROWCAP * HD) - ws)) + 255) & ~(size_t)255;
  unsigned short* Bt = (unsigned short*)(ws + ofs2);

  // Pick the widest weight-slice that fits the remaining workspace.
  size_t avail = (ws_size > ofs2) ? (ws_size - ofs2) : 0;
  int C = 64;
  const int cand[6] = {5760, 2880, 1920, 960, 320, 64};
  for (int ci = 0; ci < 6; ci++) {
    size_t need = (size_t)NEXP * cand[ci] * KDIM * 2;
    if (need <= avail) { C = cand[ci]; break; }
  }

  k_init<<<1, 64, 0, stream>>>(meta);
  k_zero<<<(TOK * HD / 4) / 256, 256, 0, stream>>>(out);
  k_router<<<TOK, 256, 0, stream>>>(x, rw, rb, meta, topk_i, topk_w);
  k_scan<<<1, 64, 0, stream>>>(meta);
  k_gather<<<NPAIR, 256, 0, stream>>>(x, topk_i, topk_w, meta, row_tok, row_w, Abuf);

  for (int c0 = 0; c0 < N1; c0 += C) {
    int cc = (C < N1 - c0) ? C : (N1 - c0);
    k_convert<<<dim3(KDIM / 64, cc / 64, NEXP), 256, 0, stream>>>(gup, Bt, N1, c0, cc);
    k_gemm<0><<<dim3(24, cc / BN), 256, 0, stream>>>(Abuf, Bt, gub, meta, row_tok, row_w,
                                                     act, nullptr, c0, cc);
  }
  for (int c0 = 0; c0 < HD; c0 += C) {
    int cc = (C < HD - c0) ? C : (HD - c0);
    k_convert<<<dim3(KDIM / 64, cc / 64, NEXP), 256, 0, stream>>>(dwn, Bt, HD, c0, cc);
    k_gemm<1><<<dim3(24, cc / BN), 256, 0, stream>>>(act, Bt, dwb, meta, row_tok, row_w,
                                                     nullptr, out, c0, cc);
  }
}